// Round 2
// baseline (528.603 us; speedup 1.0000x reference)
//
#include <hip/hip_runtime.h>

#define B 64
#define K 8
#define V 128000
#define CH 4096
#define NCH 32   // ceil(V/CH): chunk 31 holds 1024 valid elems

// One fused kernel. grid = B*NCH blocks x 256 threads.
// Phase A: every block redundantly computes num_accepted for its batch
//          (2 dependent load rounds in wave 0 — cheap, fully overlapped).
// Phase B: per-(batch,chunk) partial sum of final_dist; agent-scope store +
//          counter atomic; last block of each batch proceeds to Phase C.
// Phase C: scan 32 chunk sums -> crossing chunk -> re-read that 16 KB chunk
//          -> exact index -> write the 9-token row.
__global__ __launch_bounds__(256) void rs_fused(
    const int*   __restrict__ draft_tokens,
    const float* __restrict__ draft_probs,
    const float* __restrict__ oracle_probs,
    const float* __restrict__ uniforms,
    const float* __restrict__ sample_u,
    int*   __restrict__ done,       // [B], pre-zeroed by memset node
    float* __restrict__ chunkSums,  // [B*NCH]
    int*   __restrict__ out_tokens, // [B*(K+1)]
    int*   __restrict__ out_na)     // [B]
{
  const int b    = blockIdx.x >> 5;
  const int c    = blockIdx.x & 31;
  const int tid  = threadIdx.x;
  const int lane = tid & 63, w = tid >> 6;

  __shared__ int   s_na;
  __shared__ int   s_last;
  __shared__ float sWS[4];
  __shared__ float sT, sBase;
  __shared__ int   sC, sIdx;

  // ---------------- Phase A: num_accepted (wave 0) ----------------
  if (w == 0) {
    int accept = 0;
    if (lane < K) {
      int   t  = draft_tokens[b * K + lane];
      float pd = draft_probs [((size_t)(b * K       + lane)) * V + t];
      float po = oracle_probs[((size_t)(b * (K + 1) + lane)) * V + t];
      accept = (uniforms[b * K + lane] < fminf(1.0f, po / pd)) ? 1 : 0;
    }
    unsigned long long m    = __ballot(accept != 0) & 0xFFull;
    unsigned long long notm = (~m) & 0xFFull;
    int na = notm ? (int)__builtin_ctzll(notm) : K;  // leading accepts
    if (lane == 0) s_na = na;
  }
  __syncthreads();
  const int  na  = s_na;
  const bool acc = (na == K);
  const int  row = acc ? K : na;   // min(na, K-1) == na when na < K
  const float* orow = oracle_probs + ((size_t)(b * (K + 1) + row)) * V;
  const float* drow = draft_probs  + ((size_t)(b * K       + row)) * V;

  // ---------------- Phase B: chunk partial sum ----------------
  const int base = c * CH;
  float s = 0.f;
#pragma unroll
  for (int it = 0; it < 4; ++it) {
    int idx = base + it * 1024 + tid * 4;
    if (idx < V) {
      float4 o = *(const float4*)(orow + idx);
      if (acc) {
        s += (o.x + o.y) + (o.z + o.w);
      } else {
        float4 d = *(const float4*)(drow + idx);
        s += fmaxf(o.x - d.x, 0.f) + fmaxf(o.y - d.y, 0.f)
           + fmaxf(o.z - d.z, 0.f) + fmaxf(o.w - d.w, 0.f);
      }
    }
  }
  for (int off = 32; off > 0; off >>= 1) s += __shfl_down(s, off);
  if (lane == 0) sWS[w] = s;
  __syncthreads();
  if (tid == 0) {
    float total = (sWS[0] + sWS[1]) + (sWS[2] + sWS[3]);
    __hip_atomic_store(&chunkSums[b * NCH + c], total,
                       __ATOMIC_RELAXED, __HIP_MEMORY_SCOPE_AGENT);
    int old = __hip_atomic_fetch_add(&done[b], 1,
                                     __ATOMIC_ACQ_REL, __HIP_MEMORY_SCOPE_AGENT);
    s_last = (old == NCH - 1);
    if (c == 0) out_na[b] = na;
  }
  __syncthreads();
  if (!s_last) return;

  // ---------------- Phase C: sample (last block per batch) ----------------
  if (w == 0) {
    float v = (lane < NCH)
      ? __hip_atomic_load(&chunkSums[b * NCH + lane],
                          __ATOMIC_RELAXED, __HIP_MEMORY_SCOPE_AGENT)
      : 0.f;
    float incl = v;
    for (int off = 1; off < NCH; off <<= 1) {
      float n = __shfl_up(incl, off);
      if (lane >= off) incl += n;
    }
    float S = __shfl(incl, NCH - 1);
    float T = acc ? sample_u[b] : sample_u[b] * S;  // unnormalized threshold
    unsigned long long m = __ballot(lane < NCH && incl >= T);
    if (lane == 0) {
      sT = T;
      if (m == 0ULL) { sC = -1; sIdx = V - 1; sBase = 0.f; }
    }
    if (m != 0ULL) {
      int cs = (int)__builtin_ctzll(m);
      if (lane == cs) {
        sC = cs;
        sBase = incl - v;                 // exclusive prefix of chunk
        int fb = cs * CH + CH - 1;        // fallback: end of chunk
        sIdx = fb < V ? fb : V - 1;
      }
    }
  }
  __syncthreads();

  const int cstar = sC;
  int new_token;
  if (cstar >= 0) {
    const float T = sT;
    const int cbase  = cstar * CH;
    const int estart = cbase + tid * 16;   // 16 contiguous elems / thread
    float vals[16];
    float ps = 0.f;
#pragma unroll
    for (int j4 = 0; j4 < 4; ++j4) {
      int idx = estart + j4 * 4;
      float4 o = make_float4(0.f, 0.f, 0.f, 0.f);
      float4 d = make_float4(0.f, 0.f, 0.f, 0.f);
      if (idx < V) {
        o = *(const float4*)(orow + idx);
        if (!acc) d = *(const float4*)(drow + idx);
      }
      float v0 = acc ? o.x : fmaxf(o.x - d.x, 0.f);
      float v1 = acc ? o.y : fmaxf(o.y - d.y, 0.f);
      float v2 = acc ? o.z : fmaxf(o.z - d.z, 0.f);
      float v3 = acc ? o.w : fmaxf(o.w - d.w, 0.f);
      vals[j4 * 4 + 0] = v0; vals[j4 * 4 + 1] = v1;
      vals[j4 * 4 + 2] = v2; vals[j4 * 4 + 3] = v3;
      ps += (v0 + v1) + (v2 + v3);
    }
    float incl = ps;
    for (int off = 1; off < 64; off <<= 1) {
      float n = __shfl_up(incl, off);
      if (lane >= off) incl += n;
    }
    if (lane == 63) sWS[w] = incl;
    __syncthreads();
    float woff = 0.f;
    for (int i = 0; i < w; ++i) woff += sWS[i];
    float run = sBase + woff + (incl - ps);
    int found = -1;
#pragma unroll
    for (int j = 0; j < 16; ++j) {
      run += vals[j];
      if (found < 0 && run >= T) found = estart + j;
    }
    if (found >= 0 && found < V) atomicMin(&sIdx, found);
    __syncthreads();
    new_token = sIdx;
  } else {
    new_token = V - 1;
  }

  if (tid < K + 1) {
    int pos = tid, val;
    if (pos < na)       val = draft_tokens[b * K + pos];
    else if (pos == na) val = new_token;
    else                val = -1;
    out_tokens[b * (K + 1) + pos] = val;
  }
}

// ---------------------------------------------------------------------------
extern "C" void kernel_launch(void* const* d_in, const int* in_sizes, int n_in,
                              void* d_out, int out_size, void* d_ws, size_t ws_size,
                              hipStream_t stream) {
  const int*   draft_tokens = (const int*)  d_in[0];
  const float* draft_probs  = (const float*)d_in[1];
  /* d_in[2] = oracle_tokens (unused by the reference math) */
  const float* oracle_probs = (const float*)d_in[3];
  const float* uniforms     = (const float*)d_in[4];
  const float* sample_u     = (const float*)d_in[5];
  /* d_in[6] = num_draft_tokens == K (hardcoded) */

  int* out_tokens = (int*)d_out;               // [B, K+1] = 576
  int* out_na     = out_tokens + B * (K + 1);  // [B]      = 64

  int*   done      = (int*)d_ws;               // [B]
  float* chunkSums = (float*)d_ws + B;         // [B*NCH]

  hipMemsetAsync(done, 0, B * sizeof(int), stream);
  rs_fused<<<B * NCH, 256, 0, stream>>>(draft_tokens, draft_probs, oracle_probs,
                                        uniforms, sample_u, done, chunkSums,
                                        out_tokens, out_na);
}